// Round 2
// baseline (338.358 us; speedup 1.0000x reference)
//
#include <hip/hip_runtime.h>
#include <hip/hip_bf16.h>

// B=2, S=2048, D=1024, H=16, HD=64. fp32 in, fp32 out, bf16-tolerance threshold.
// Pipeline: convert->bf16 | QKV GEMM (mfma bf16) | RoPE | V-transpose | flash attn | out GEMM.

typedef unsigned short u16;
typedef short bf16x8 __attribute__((ext_vector_type(8)));
typedef float f32x4 __attribute__((ext_vector_type(4)));

__device__ __forceinline__ u16 f2bf(float f) {
    unsigned u = __builtin_bit_cast(unsigned, f);
    u += 0x7fffu + ((u >> 16) & 1u);   // RNE
    return (u16)(u >> 16);
}
__device__ __forceinline__ float bf2f(u16 h) {
    unsigned u = ((unsigned)h) << 16;
    return __builtin_bit_cast(float, u);
}

// ---------------- fp32 -> bf16 convert (4 elems/thread, exact grid) ----------------
__global__ __launch_bounds__(256) void f32_to_bf16_k(const float* __restrict__ in,
                                                     u16* __restrict__ out) {
    int i = (blockIdx.x * 256 + threadIdx.x) * 4;
    float4 v = *(const float4*)(in + i);
    uint2 o;
    o.x = (unsigned)f2bf(v.x) | ((unsigned)f2bf(v.y) << 16);
    o.y = (unsigned)f2bf(v.z) | ((unsigned)f2bf(v.w) << 16);
    *(uint2*)(out + i) = o;
}

// ---------------- bf16 GEMM: C[m][n] = sum_k A[m][k]*Bw[n][k] (+bias epilogue) -----
template <int EPI>
__global__ __launch_bounds__(256) void gemm_bt(const u16* __restrict__ A,
                                               const u16* __restrict__ Bw,
                                               const float* __restrict__ bias0,
                                               const float* __restrict__ bias1,
                                               const float* __restrict__ bias2,
                                               u16* __restrict__ outB,
                                               float* __restrict__ outF,
                                               int M, int N, int K) {
    __shared__ __align__(16) u16 As[128 * 32];
    __shared__ __align__(16) u16 Bs[128 * 32];
    const int tid = threadIdx.x;
    const int lane = tid & 63;
    const int w = tid >> 6;
    const int wr = w >> 1, wc = w & 1;
    const int lr = lane & 15, lg = lane >> 4;
    const int nbn = N >> 7;
    const int m0 = (blockIdx.x / nbn) << 7;
    const int n0 = (blockIdx.x % nbn) << 7;

    f32x4 acc[4][4] = {};

    const u16* aptr[2];
    const u16* bptr[2];
    int ldsoff[2];
#pragma unroll
    for (int i = 0; i < 2; ++i) {
        int c = (w * 2 + i) * 64 + lane;
        int row = c >> 2, kc = (c & 3) << 3;
        aptr[i] = A + (size_t)(m0 + row) * K + kc;
        bptr[i] = Bw + (size_t)(n0 + row) * K + kc;
        ldsoff[i] = (w * 2 + i) * 512;
    }

    for (int k0 = 0; k0 < K; k0 += 32) {
#pragma unroll
        for (int i = 0; i < 2; ++i) {
            __builtin_amdgcn_global_load_lds(
                (const __attribute__((address_space(1))) void*)(aptr[i] + k0),
                (__attribute__((address_space(3))) void*)(As + ldsoff[i]), 16, 0, 0);
            __builtin_amdgcn_global_load_lds(
                (const __attribute__((address_space(1))) void*)(bptr[i] + k0),
                (__attribute__((address_space(3))) void*)(Bs + ldsoff[i]), 16, 0, 0);
        }
        __syncthreads();
        bf16x8 af[4], bfr[4];
#pragma unroll
        for (int i = 0; i < 4; ++i)
            af[i] = *(const bf16x8*)(As + (wr * 64 + i * 16 + lr) * 32 + lg * 8);
#pragma unroll
        for (int j = 0; j < 4; ++j)
            bfr[j] = *(const bf16x8*)(Bs + (wc * 64 + j * 16 + lr) * 32 + lg * 8);
#pragma unroll
        for (int i = 0; i < 4; ++i)
#pragma unroll
            for (int j = 0; j < 4; ++j)
                acc[i][j] = __builtin_amdgcn_mfma_f32_16x16x32_bf16(af[i], bfr[j],
                                                                    acc[i][j], 0, 0, 0);
        __syncthreads();
    }

#pragma unroll
    for (int i = 0; i < 4; ++i) {
        int mg = m0 + wr * 64 + i * 16 + lg * 4;
#pragma unroll
        for (int j = 0; j < 4; ++j) {
            int ng = n0 + wc * 64 + j * 16 + lr;
            float bias;
            if (EPI == 0)
                bias = (ng < 1024) ? bias0[ng] : (ng < 2048) ? bias1[ng - 1024]
                                                             : bias2[ng - 2048];
            else
                bias = bias0[ng];
#pragma unroll
            for (int r = 0; r < 4; ++r) {
                float v = acc[i][j][r] + bias;
                if (EPI == 0)
                    outB[(size_t)(mg + r) * N + ng] = f2bf(v);
                else
                    outF[(size_t)(mg + r) * N + ng] = v;
            }
        }
    }
}

// ---------------- RoPE in-place on q,k halves of qkv[4096][3072] -------------------
__global__ __launch_bounds__(256) void rope_k(u16* qkv, const int* __restrict__ days) {
    int p = blockIdx.x * 256 + threadIdx.x;
    int m = p >> 10;
    int r = p & 1023;
    int mat = r >> 9;
    int hh = (r >> 5) & 15;
    int i = r & 31;
    int d = days[m];
    int ad = d < 0 ? -d : d;
    float pos = (float)(ad > 2047 ? 2047 : ad);
    float inv = exp2f((float)i * -0.41524101186091903f);
    float f = pos * inv;
    float sn, cs;
    __sincosf(f, &sn, &cs);
    size_t base = (size_t)m * 3072 + mat * 1024 + hh * 64 + i;
    float x1 = bf2f(qkv[base]);
    float x2 = bf2f(qkv[base + 32]);
    qkv[base] = f2bf(x1 * cs - x2 * sn);
    qkv[base + 32] = f2bf(x2 * cs + x1 * sn);
}

// ---------------- V transpose: qkv v-region -> Vt[b,h,hd,s] ------------------------
__global__ __launch_bounds__(256) void v_transpose_k(const u16* __restrict__ qkv,
                                                     u16* __restrict__ vt) {
    __shared__ u16 tile[64][66];
    int st = blockIdx.x & 31;
    int bh = blockIdx.x >> 5;
    int b = bh >> 4, h = bh & 15;
    int s0 = st * 64;
    int t = threadIdx.x;
#pragma unroll
    for (int it = 0; it < 16; ++it) {
        int idx = it * 256 + t;
        int sr = idx >> 6, c = idx & 63;
        tile[sr][c] = qkv[(size_t)(b * 2048 + s0 + sr) * 3072 + 2048 + h * 64 + c];
    }
    __syncthreads();
#pragma unroll
    for (int it = 0; it < 16; ++it) {
        int idx = it * 256 + t;
        int hd = idx >> 6, sc = idx & 63;
        vt[((size_t)(bh * 64 + hd)) * 2048 + s0 + sc] = tile[sc][hd];
    }
}

// ---------------- flash attention v2: swapped QK^T, fixed-max softmax --------------
// Block = 4 waves; wave owns 16 q-rows, KV tile = 64 keys.
// QK^T swapped: D = S^T, lane(lr,lg) holds S[key=st*16+lg*4+r][q=lr] -> softmax is
// in-lane (16 elems) + NO per-tile cross-lane reduce. Fixed max M0=12 (scores are
// O(1); exp headroom to 88) -> no online rescale at all. l summed in-lane, combined
// once at the end (2 shuffles). P redistributed to A-layout via 2KB/wave LDS with
// 16B-chunk XOR swizzle (write 2-way free, read at b128 structural minimum).
__global__ __launch_bounds__(256) void attn_k(const u16* __restrict__ qkv,
                                              const u16* __restrict__ vt,
                                              const int* __restrict__ days,
                                              const float* __restrict__ decay_p,
                                              u16* __restrict__ attn_out) {
    __shared__ __align__(16) u16 P_lds[4][16 * 64];
    const int tid = threadIdx.x;
    const int lane = tid & 63;
    const int w = tid >> 6;
    const int lr = lane & 15, lg = lane >> 4;
    const int qt = blockIdx.x & 31;   // 64-row q block
    const int bh = blockIdx.x >> 5;
    const int b = bh >> 4, h = bh & 15;
    const int qbase = qt * 64 + w * 16;
    const float rate = decay_p[0];

    const u16* qmat = qkv + (size_t)b * 2048 * 3072 + h * 64;
    const u16* kmat = qmat + 1024;
    const u16* vtm = vt + (size_t)bh * 64 * 2048;
    const int* db = days + b * 2048;

    // Q as B-fragment (col = lr = query), resident in regs for the whole kernel
    bf16x8 bq0, bq1;
    {
        const u16* qp = qmat + (size_t)(qbase + lr) * 3072 + lg * 8;
        bq0 = *(const bf16x8*)qp;
        bq1 = *(const bf16x8*)(qp + 32);
    }
    const int qg_l = qbase + lr;  // this lane's softmax query
    const float dq = (float)db[qg_l];
    // v = s * exp((dk-dq)*rate) / 8 = s * exp(dk*rate - (dq*rate + ln8))
    const float dq_off = dq * rate + 2.0794415416798357f;
    const float M0 = 12.0f;

    float l_part = 0.f;
    f32x4 acc[4] = {};  // acc[c][r] = O[q=qbase+lg*4+r][hd=c*16+lr]

    const int nkt = qt + 1;
    for (int kt = 0; kt < nkt; ++kt) {
        const int k0 = kt * 64;
        // ---- QK^T (swapped): St[key][q] per 16-key subtile ----
        f32x4 st_acc[4];
        __builtin_amdgcn_s_setprio(1);
#pragma unroll
        for (int st = 0; st < 4; ++st) {
            const u16* kp = kmat + (size_t)(k0 + st * 16 + lr) * 3072 + lg * 8;
            bf16x8 ka0 = *(const bf16x8*)kp;
            bf16x8 ka1 = *(const bf16x8*)(kp + 32);
            f32x4 t = {};
            t = __builtin_amdgcn_mfma_f32_16x16x32_bf16(ka0, bq0, t, 0, 0, 0);
            t = __builtin_amdgcn_mfma_f32_16x16x32_bf16(ka1, bq1, t, 0, 0, 0);
            st_acc[st] = t;
        }
        __builtin_amdgcn_s_setprio(0);
        // ---- decay * scale, fixed-max exp ----
        float p[4][4];
#pragma unroll
        for (int st = 0; st < 4; ++st) {
            int4 dk4 = *(const int4*)(db + k0 + st * 16 + lg * 4);
#pragma unroll
            for (int r = 0; r < 4; ++r) {
                float dkf = (float)((&dk4.x)[r]);
                float decay = __expf(dkf * rate - dq_off);  // includes /8
                float v = st_acc[st][r] * decay;
                p[st][r] = __expf(v - M0);
            }
        }
        if (kt == nkt - 1) {  // only the diagonal tile needs masking
#pragma unroll
            for (int st = 0; st < 4; ++st)
#pragma unroll
                for (int r = 0; r < 4; ++r) {
                    int kg = k0 + st * 16 + lg * 4 + r;
                    p[st][r] = (kg <= qg_l) ? p[st][r] : 0.f;
                }
        }
#pragma unroll
        for (int st = 0; st < 4; ++st)
#pragma unroll
            for (int r = 0; r < 4; ++r) l_part += p[st][r];
        // ---- P (S^T layout) -> bf16 -> LDS (XOR-swizzled) ----
#pragma unroll
        for (int st = 0; st < 4; ++st) {
            uint2 pk;
            pk.x = (unsigned)f2bf(p[st][0]) | ((unsigned)f2bf(p[st][1]) << 16);
            pk.y = (unsigned)f2bf(p[st][2]) | ((unsigned)f2bf(p[st][3]) << 16);
            int chunk = st * 2 + (lg >> 1);
            int idx = lr * 64 + ((chunk ^ (lr & 7)) << 3) + ((lg & 1) << 2);
            *(uint2*)&P_lds[w][idx] = pk;
        }
        // ---- PV: A = P rows (q=lr), B = Vt cols ----
        __builtin_amdgcn_s_setprio(1);
#pragma unroll
        for (int pv = 0; pv < 2; ++pv) {
            int chunk = pv * 4 + lg;
            bf16x8 pa = *(const bf16x8*)&P_lds[w][lr * 64 + ((chunk ^ (lr & 7)) << 3)];
#pragma unroll
            for (int c = 0; c < 4; ++c) {
                bf16x8 bv = *(const bf16x8*)(vtm + (size_t)(c * 16 + lr) * 2048 + k0 +
                                             pv * 32 + lg * 8);
                acc[c] = __builtin_amdgcn_mfma_f32_16x16x32_bf16(pa, bv, acc[c], 0, 0, 0);
            }
        }
        __builtin_amdgcn_s_setprio(0);
    }

    // combine l across the 4 lanes sharing a query, then fetch per-output-row l
    float l_full = l_part + __shfl_xor(l_part, 16);
    l_full += __shfl_xor(l_full, 32);
    float inv[4];
#pragma unroll
    for (int r = 0; r < 4; ++r) inv[r] = 1.0f / __shfl(l_full, lg * 4 + r);
#pragma unroll
    for (int c = 0; c < 4; ++c)
#pragma unroll
        for (int r = 0; r < 4; ++r) {
            const int qg = qbase + lg * 4 + r;
            attn_out[(size_t)(b * 2048 + qg) * 1024 + h * 64 + c * 16 + lr] =
                f2bf(acc[c][r] * inv[r]);
        }
}

// ---------------- launch -----------------------------------------------------------
extern "C" void kernel_launch(void* const* d_in, const int* in_sizes, int n_in,
                              void* d_out, int out_size, void* d_ws, size_t ws_size,
                              hipStream_t stream) {
    const float* x = (const float*)d_in[0];
    const float* Wq = (const float*)d_in[1];
    const float* bq = (const float*)d_in[2];
    const float* Wk = (const float*)d_in[3];
    const float* bk = (const float*)d_in[4];
    const float* Wv = (const float*)d_in[5];
    const float* bv = (const float*)d_in[6];
    const float* Wo = (const float*)d_in[7];
    const float* bo = (const float*)d_in[8];
    const float* decay = (const float*)d_in[9];
    const int* days = (const int*)d_in[11];
    float* out = (float*)d_out;

    char* ws = (char*)d_ws;
    u16* xb = (u16*)(ws);                   //  8 MB: x bf16 [4096][1024]
    u16* wqkv = (u16*)(ws + 8388608);       //  6 MB: [Wq;Wk;Wv] bf16 [3072][1024]
    u16* wo = (u16*)(ws + 14680064);        //  2 MB: Wo bf16 [1024][1024]
    u16* qkvb = (u16*)(ws + 16777216);      // 24 MB: qkv bf16 [4096][3072]
    u16* vtb = (u16*)(ws + 41943040);       //  8 MB: Vt bf16 [32][64][2048]
    u16* attb = (u16*)(ws + 50331648);      //  8 MB: attn out bf16 [4096][1024]

    f32_to_bf16_k<<<4096, 256, 0, stream>>>(x, xb);
    f32_to_bf16_k<<<1024, 256, 0, stream>>>(Wq, wqkv);
    f32_to_bf16_k<<<1024, 256, 0, stream>>>(Wk, wqkv + 1048576);
    f32_to_bf16_k<<<1024, 256, 0, stream>>>(Wv, wqkv + 2097152);
    f32_to_bf16_k<<<1024, 256, 0, stream>>>(Wo, wo);

    gemm_bt<0><<<768, 256, 0, stream>>>(xb, wqkv, bq, bk, bv, qkvb, nullptr, 4096,
                                        3072, 1024);
    rope_k<<<16384, 256, 0, stream>>>(qkvb, days);
    v_transpose_k<<<1024, 256, 0, stream>>>(qkvb, vtb);
    attn_k<<<1024, 256, 0, stream>>>(qkvb, vtb, days, decay, attb);
    gemm_bt<1><<<256, 256, 0, stream>>>(attb, wo, bo, nullptr, nullptr, nullptr, out,
                                        4096, 1024, 1024);
}

// Round 3
// 158.340 us; speedup vs baseline: 2.1369x; 2.1369x over previous
//
#include <hip/hip_runtime.h>
#include <hip/hip_bf16.h>

// B=2, S=2048, D=1024, H=16, HD=64. fp32 in, fp32 out, bf16-tolerance threshold.
// Pipeline: convert->bf16 | QKV GEMM (mfma bf16) | RoPE | V-transpose | flash attn | out GEMM.

typedef unsigned short u16;
typedef short bf16x8 __attribute__((ext_vector_type(8)));
typedef float f32x4 __attribute__((ext_vector_type(4)));

__device__ __forceinline__ u16 f2bf(float f) {
    unsigned u = __builtin_bit_cast(unsigned, f);
    u += 0x7fffu + ((u >> 16) & 1u);   // RNE
    return (u16)(u >> 16);
}
__device__ __forceinline__ float bf2f(u16 h) {
    unsigned u = ((unsigned)h) << 16;
    return __builtin_bit_cast(float, u);
}

// ---------------- fp32 -> bf16 convert (4 elems/thread, exact grid) ----------------
__global__ __launch_bounds__(256) void f32_to_bf16_k(const float* __restrict__ in,
                                                     u16* __restrict__ out) {
    int i = (blockIdx.x * 256 + threadIdx.x) * 4;
    float4 v = *(const float4*)(in + i);
    uint2 o;
    o.x = (unsigned)f2bf(v.x) | ((unsigned)f2bf(v.y) << 16);
    o.y = (unsigned)f2bf(v.z) | ((unsigned)f2bf(v.w) << 16);
    *(uint2*)(out + i) = o;
}

// ---------------- bf16 GEMM: C[m][n] = sum_k A[m][k]*Bw[n][k] (+bias epilogue) -----
template <int EPI>
__global__ __launch_bounds__(256) void gemm_bt(const u16* __restrict__ A,
                                               const u16* __restrict__ Bw,
                                               const float* __restrict__ bias0,
                                               const float* __restrict__ bias1,
                                               const float* __restrict__ bias2,
                                               u16* __restrict__ outB,
                                               float* __restrict__ outF,
                                               int M, int N, int K) {
    __shared__ __align__(16) u16 As[128 * 32];
    __shared__ __align__(16) u16 Bs[128 * 32];
    const int tid = threadIdx.x;
    const int lane = tid & 63;
    const int w = tid >> 6;
    const int wr = w >> 1, wc = w & 1;
    const int lr = lane & 15, lg = lane >> 4;
    const int nbn = N >> 7;
    const int m0 = (blockIdx.x / nbn) << 7;
    const int n0 = (blockIdx.x % nbn) << 7;

    f32x4 acc[4][4] = {};

    const u16* aptr[2];
    const u16* bptr[2];
    int ldsoff[2];
#pragma unroll
    for (int i = 0; i < 2; ++i) {
        int c = (w * 2 + i) * 64 + lane;
        int row = c >> 2, kc = (c & 3) << 3;
        aptr[i] = A + (size_t)(m0 + row) * K + kc;
        bptr[i] = Bw + (size_t)(n0 + row) * K + kc;
        ldsoff[i] = (w * 2 + i) * 512;
    }

    for (int k0 = 0; k0 < K; k0 += 32) {
#pragma unroll
        for (int i = 0; i < 2; ++i) {
            __builtin_amdgcn_global_load_lds(
                (const __attribute__((address_space(1))) void*)(aptr[i] + k0),
                (__attribute__((address_space(3))) void*)(As + ldsoff[i]), 16, 0, 0);
            __builtin_amdgcn_global_load_lds(
                (const __attribute__((address_space(1))) void*)(bptr[i] + k0),
                (__attribute__((address_space(3))) void*)(Bs + ldsoff[i]), 16, 0, 0);
        }
        __syncthreads();
        bf16x8 af[4], bfr[4];
#pragma unroll
        for (int i = 0; i < 4; ++i)
            af[i] = *(const bf16x8*)(As + (wr * 64 + i * 16 + lr) * 32 + lg * 8);
#pragma unroll
        for (int j = 0; j < 4; ++j)
            bfr[j] = *(const bf16x8*)(Bs + (wc * 64 + j * 16 + lr) * 32 + lg * 8);
#pragma unroll
        for (int i = 0; i < 4; ++i)
#pragma unroll
            for (int j = 0; j < 4; ++j)
                acc[i][j] = __builtin_amdgcn_mfma_f32_16x16x32_bf16(af[i], bfr[j],
                                                                    acc[i][j], 0, 0, 0);
        __syncthreads();
    }

#pragma unroll
    for (int i = 0; i < 4; ++i) {
        int mg = m0 + wr * 64 + i * 16 + lg * 4;
#pragma unroll
        for (int j = 0; j < 4; ++j) {
            int ng = n0 + wc * 64 + j * 16 + lr;
            float bias;
            if (EPI == 0)
                bias = (ng < 1024) ? bias0[ng] : (ng < 2048) ? bias1[ng - 1024]
                                                             : bias2[ng - 2048];
            else
                bias = bias0[ng];
#pragma unroll
            for (int r = 0; r < 4; ++r) {
                float v = acc[i][j][r] + bias;
                if (EPI == 0)
                    outB[(size_t)(mg + r) * N + ng] = f2bf(v);
                else
                    outF[(size_t)(mg + r) * N + ng] = v;
            }
        }
    }
}

// ---------------- RoPE in-place on q,k halves of qkv[4096][3072] -------------------
__global__ __launch_bounds__(256) void rope_k(u16* qkv, const int* __restrict__ days) {
    int p = blockIdx.x * 256 + threadIdx.x;
    int m = p >> 10;
    int r = p & 1023;
    int mat = r >> 9;
    int hh = (r >> 5) & 15;
    int i = r & 31;
    int d = days[m];
    int ad = d < 0 ? -d : d;
    float pos = (float)(ad > 2047 ? 2047 : ad);
    float inv = exp2f((float)i * -0.41524101186091903f);
    float f = pos * inv;
    float sn, cs;
    __sincosf(f, &sn, &cs);
    size_t base = (size_t)m * 3072 + mat * 1024 + hh * 64 + i;
    float x1 = bf2f(qkv[base]);
    float x2 = bf2f(qkv[base + 32]);
    qkv[base] = f2bf(x1 * cs - x2 * sn);
    qkv[base + 32] = f2bf(x2 * cs + x1 * sn);
}

// ---------------- V transpose: qkv v-region -> Vt[b,h,hd,s] ------------------------
__global__ __launch_bounds__(256) void v_transpose_k(const u16* __restrict__ qkv,
                                                     u16* __restrict__ vt) {
    __shared__ u16 tile[64][66];
    int st = blockIdx.x & 31;
    int bh = blockIdx.x >> 5;
    int b = bh >> 4, h = bh & 15;
    int s0 = st * 64;
    int t = threadIdx.x;
#pragma unroll
    for (int it = 0; it < 16; ++it) {
        int idx = it * 256 + t;
        int sr = idx >> 6, c = idx & 63;
        tile[sr][c] = qkv[(size_t)(b * 2048 + s0 + sr) * 3072 + 2048 + h * 64 + c];
    }
    __syncthreads();
#pragma unroll
    for (int it = 0; it < 16; ++it) {
        int idx = it * 256 + t;
        int hd = idx >> 6, sc = idx & 63;
        vt[((size_t)(bh * 64 + hd)) * 2048 + s0 + sc] = tile[sc][hd];
    }
}

// ---------------- flash attention v3 -----------------------------------------------
// Balanced causal pairing: block j handles q-tiles {j, 31-j} (33 tile-iters, uniform).
// K/V tiles staged to LDS via global_load_lds (linear dest + inverse-swizzled global
// source; reads apply the same XOR -> conflict-free), double-buffered with counted
// vmcnt(4) + raw s_barrier so prefetch loads stay in flight across barriers.
// Per wave: 16 q-rows of each tile; swapped QK^T (lane-local softmax, fixed max).

__device__ __forceinline__ void attn_tile(const u16* __restrict__ Ks,
                                          const u16* __restrict__ Vs,
                                          u16* __restrict__ Pw,
                                          const int* __restrict__ dbk,
                                          bf16x8 bq0, bf16x8 bq1, float dq_off,
                                          int qrel, bool domask, float rate,
                                          float& l_part, f32x4* acc, int lr, int lg) {
    f32x4 st_acc[4];
    __builtin_amdgcn_s_setprio(1);
#pragma unroll
    for (int st = 0; st < 4; ++st) {
        const int r2 = st * 16 + lr;
        const u16* kr = Ks + r2 * 64;
        bf16x8 ka0 = *(const bf16x8*)(kr + ((lg ^ (r2 & 7)) << 3));
        bf16x8 ka1 = *(const bf16x8*)(kr + (((4 + lg) ^ (r2 & 7)) << 3));
        f32x4 t = {};
        t = __builtin_amdgcn_mfma_f32_16x16x32_bf16(ka0, bq0, t, 0, 0, 0);
        t = __builtin_amdgcn_mfma_f32_16x16x32_bf16(ka1, bq1, t, 0, 0, 0);
        st_acc[st] = t;
    }
    __builtin_amdgcn_s_setprio(0);
    float p[4][4];
#pragma unroll
    for (int st = 0; st < 4; ++st) {
        int4 dk4 = *(const int4*)(dbk + st * 16 + lg * 4);
#pragma unroll
        for (int r = 0; r < 4; ++r) {
            float dkf = (float)((&dk4.x)[r]);
            float decay = __expf(dkf * rate - dq_off);  // includes the /8 scale
            float v = st_acc[st][r] * decay;
            p[st][r] = __expf(v - 12.0f);
        }
    }
    if (domask) {
#pragma unroll
        for (int st = 0; st < 4; ++st)
#pragma unroll
            for (int r = 0; r < 4; ++r)
                p[st][r] = (st * 16 + lg * 4 + r <= qrel) ? p[st][r] : 0.f;
    }
#pragma unroll
    for (int st = 0; st < 4; ++st)
#pragma unroll
        for (int r = 0; r < 4; ++r) l_part += p[st][r];
#pragma unroll
    for (int st = 0; st < 4; ++st) {
        uint2 pk;
        pk.x = (unsigned)f2bf(p[st][0]) | ((unsigned)f2bf(p[st][1]) << 16);
        pk.y = (unsigned)f2bf(p[st][2]) | ((unsigned)f2bf(p[st][3]) << 16);
        int chunk = st * 2 + (lg >> 1);
        int idx = lr * 64 + ((chunk ^ (lr & 7)) << 3) + ((lg & 1) << 2);
        *(uint2*)&Pw[idx] = pk;
    }
    __builtin_amdgcn_s_setprio(1);
#pragma unroll
    for (int pv = 0; pv < 2; ++pv) {
        int chunk = pv * 4 + lg;
        bf16x8 pa = *(const bf16x8*)&Pw[lr * 64 + ((chunk ^ (lr & 7)) << 3)];
#pragma unroll
        for (int c = 0; c < 4; ++c) {
            const int r3 = c * 16 + lr;
            bf16x8 bv =
                *(const bf16x8*)(Vs + r3 * 64 + ((chunk ^ (r3 & 7)) << 3));
            acc[c] = __builtin_amdgcn_mfma_f32_16x16x32_bf16(pa, bv, acc[c], 0, 0, 0);
        }
    }
    __builtin_amdgcn_s_setprio(0);
}

__global__ __launch_bounds__(256, 2) void attn_k(const u16* __restrict__ qkv,
                                                 const u16* __restrict__ vt,
                                                 const int* __restrict__ days,
                                                 const float* __restrict__ decay_p,
                                                 u16* __restrict__ attn_out) {
    __shared__ __align__(16) u16 Ks[2][4096];
    __shared__ __align__(16) u16 Vs[2][4096];
    __shared__ __align__(16) u16 Plds[4][1024];
    const int tid = threadIdx.x;
    const int lane = tid & 63;
    const int w = tid >> 6;
    const int lr = lane & 15, lg = lane >> 4;
    const int j = blockIdx.x & 15;
    const int bh = blockIdx.x >> 4;
    const int b = bh >> 4, h = bh & 15;
    const int qbA = j * 64 + w * 16;
    const int qbB = (31 - j) * 64 + w * 16;
    const float rate = decay_p[0];

    const u16* qmat = qkv + (size_t)b * 2048 * 3072 + h * 64;
    const u16* kmat = qmat + 1024;
    const u16* vtm = vt + (size_t)bh * 64 * 2048;
    const int* db = days + b * 2048;

    // staging descriptors: chunk cp in [0,512), slot (row cp>>3, 16B-chunk cp&7).
    // LDS dest is linear; global source pre-applies the read-side XOR swizzle.
    const int cp0 = (w * 2 + 0) * 64 + lane;
    const int cp1 = (w * 2 + 1) * 64 + lane;
    const int r0 = cp0 >> 3, c0 = cp0 & 7;
    const int r1 = cp1 >> 3, c1 = cp1 & 7;
    const u16* ksrc0 = kmat + (size_t)r0 * 3072 + ((c0 ^ (r0 & 7)) << 3);
    const u16* ksrc1 = kmat + (size_t)r1 * 3072 + ((c1 ^ (r1 & 7)) << 3);
    const u16* vsrc0 = vtm + (size_t)r0 * 2048 + ((c0 ^ (r0 & 7)) << 3);
    const u16* vsrc1 = vtm + (size_t)r1 * 2048 + ((c1 ^ (r1 & 7)) << 3);
    const int doff0 = (w * 2 + 0) * 512;
    const int doff1 = (w * 2 + 1) * 512;

#define STAGE(T, BUF)                                                                  \
    do {                                                                               \
        __builtin_amdgcn_global_load_lds(                                              \
            (const __attribute__((address_space(1))) void*)(ksrc0 +                    \
                                                            (size_t)(T) * 64 * 3072), \
            (__attribute__((address_space(3))) void*)(&Ks[BUF][doff0]), 16, 0, 0);     \
        __builtin_amdgcn_global_load_lds(                                              \
            (const __attribute__((address_space(1))) void*)(ksrc1 +                    \
                                                            (size_t)(T) * 64 * 3072), \
            (__attribute__((address_space(3))) void*)(&Ks[BUF][doff1]), 16, 0, 0);     \
        __builtin_amdgcn_global_load_lds(                                              \
            (const __attribute__((address_space(1))) void*)(vsrc0 + (size_t)(T) * 64), \
            (__attribute__((address_space(3))) void*)(&Vs[BUF][doff0]), 16, 0, 0);     \
        __builtin_amdgcn_global_load_lds(                                              \
            (const __attribute__((address_space(1))) void*)(vsrc1 + (size_t)(T) * 64), \
            (__attribute__((address_space(3))) void*)(&Vs[BUF][doff1]), 16, 0, 0);     \
    } while (0)

    // Q fragments for both q-tiles, resident all kernel
    bf16x8 bqA0, bqA1, bqB0, bqB1;
    {
        const u16* qpA = qmat + (size_t)(qbA + lr) * 3072 + lg * 8;
        bqA0 = *(const bf16x8*)qpA;
        bqA1 = *(const bf16x8*)(qpA + 32);
        const u16* qpB = qmat + (size_t)(qbB + lr) * 3072 + lg * 8;
        bqB0 = *(const bf16x8*)qpB;
        bqB1 = *(const bf16x8*)(qpB + 32);
    }
    const float ln8 = 2.0794415416798357f;
    const float dq_offA = (float)db[qbA + lr] * rate + ln8;
    const float dq_offB = (float)db[qbB + lr] * rate + ln8;

    float lA = 0.f, lB = 0.f;
    f32x4 accA[4] = {};
    f32x4 accB[4] = {};

    const int nkt = 32 - j;  // kt = 0 .. 31-j ; A participates while kt <= j
    STAGE(0, 0);
    for (int it = 0; it < nkt; ++it) {
        const int cur = it & 1;
        if (it + 1 < nkt) {
            STAGE(it + 1, cur ^ 1);
            asm volatile("s_waitcnt vmcnt(4)" ::: "memory");
        } else {
            asm volatile("s_waitcnt vmcnt(0)" ::: "memory");
        }
        __builtin_amdgcn_s_barrier();
        const int* dbk = db + it * 64;
        attn_tile(Ks[cur], Vs[cur], Plds[w], dbk, bqB0, bqB1, dq_offB, w * 16 + lr,
                  it == nkt - 1, rate, lB, accB, lr, lg);
        if (it <= j)
            attn_tile(Ks[cur], Vs[cur], Plds[w], dbk, bqA0, bqA1, dq_offA, w * 16 + lr,
                      it == j, rate, lA, accA, lr, lg);
        __builtin_amdgcn_s_barrier();
    }
#undef STAGE

    // epilogue: combine l across lg, write O for both tiles
#pragma unroll
    for (int t = 0; t < 2; ++t) {
        float lp = t ? lA : lB;
        f32x4* acc = t ? accA : accB;
        const int qb = t ? qbA : qbB;
        float l_full = lp + __shfl_xor(lp, 16);
        l_full += __shfl_xor(l_full, 32);
        float inv_[4];
#pragma unroll
        for (int r = 0; r < 4; ++r) inv_[r] = 1.0f / __shfl(l_full, lg * 4 + r);
#pragma unroll
        for (int c = 0; c < 4; ++c)
#pragma unroll
            for (int r = 0; r < 4; ++r) {
                const int qg = qb + lg * 4 + r;
                attn_out[(size_t)(b * 2048 + qg) * 1024 + h * 64 + c * 16 + lr] =
                    f2bf(acc[c][r] * inv_[r]);
            }
    }
}

// ---------------- launch -----------------------------------------------------------
extern "C" void kernel_launch(void* const* d_in, const int* in_sizes, int n_in,
                              void* d_out, int out_size, void* d_ws, size_t ws_size,
                              hipStream_t stream) {
    const float* x = (const float*)d_in[0];
    const float* Wq = (const float*)d_in[1];
    const float* bq = (const float*)d_in[2];
    const float* Wk = (const float*)d_in[3];
    const float* bk = (const float*)d_in[4];
    const float* Wv = (const float*)d_in[5];
    const float* bv = (const float*)d_in[6];
    const float* Wo = (const float*)d_in[7];
    const float* bo = (const float*)d_in[8];
    const float* decay = (const float*)d_in[9];
    const int* days = (const int*)d_in[11];
    float* out = (float*)d_out;

    char* ws = (char*)d_ws;
    u16* xb = (u16*)(ws);                   //  8 MB: x bf16 [4096][1024]
    u16* wqkv = (u16*)(ws + 8388608);       //  6 MB: [Wq;Wk;Wv] bf16 [3072][1024]
    u16* wo = (u16*)(ws + 14680064);        //  2 MB: Wo bf16 [1024][1024]
    u16* qkvb = (u16*)(ws + 16777216);      // 24 MB: qkv bf16 [4096][3072]
    u16* vtb = (u16*)(ws + 41943040);       //  8 MB: Vt bf16 [32][64][2048]
    u16* attb = (u16*)(ws + 50331648);      //  8 MB: attn out bf16 [4096][1024]

    f32_to_bf16_k<<<4096, 256, 0, stream>>>(x, xb);
    f32_to_bf16_k<<<1024, 256, 0, stream>>>(Wq, wqkv);
    f32_to_bf16_k<<<1024, 256, 0, stream>>>(Wk, wqkv + 1048576);
    f32_to_bf16_k<<<1024, 256, 0, stream>>>(Wv, wqkv + 2097152);
    f32_to_bf16_k<<<1024, 256, 0, stream>>>(Wo, wo);

    gemm_bt<0><<<768, 256, 0, stream>>>(xb, wqkv, bq, bk, bv, qkvb, nullptr, 4096,
                                        3072, 1024);
    rope_k<<<16384, 256, 0, stream>>>(qkvb, days);
    v_transpose_k<<<1024, 256, 0, stream>>>(qkvb, vtb);
    attn_k<<<512, 256, 0, stream>>>(qkvb, vtb, days, decay, attb);
    gemm_bt<1><<<256, 256, 0, stream>>>(attb, wo, bo, nullptr, nullptr, nullptr, out,
                                        4096, 1024, 1024);
}